// Round 1
// baseline (77.157 us; speedup 1.0000x reference)
//
#include <hip/hip_runtime.h>

using u16 = unsigned short;
typedef __bf16 bf16x8 __attribute__((ext_vector_type(8)));
typedef __bf16 bf16x2 __attribute__((ext_vector_type(2)));
typedef float  f32x4  __attribute__((ext_vector_type(4)));
typedef float  f32x16 __attribute__((ext_vector_type(16)));

#define MFMA16x16x32 __builtin_amdgcn_mfma_f32_16x16x32_bf16
#define MFMA32x32x16 __builtin_amdgcn_mfma_f32_32x32x16_bf16

#if __has_builtin(__builtin_amdgcn_exp2f)
#define EXP2 __builtin_amdgcn_exp2f
#else
#define EXP2 exp2f
#endif

// fp32 -> bf16 round-to-nearest-even (bit math; finite inputs only)
static __device__ __forceinline__ unsigned f2bf_u(float f){
  unsigned x = __builtin_bit_cast(unsigned, f);
  return (x + 0x7fffu + ((x >> 16) & 1u)) >> 16;
}

// async global->LDS, 16B per lane; dest is wave-uniform base + lane*16
static __device__ __forceinline__ void gll16(const void* g, void* l){
  __builtin_amdgcn_global_load_lds((const __attribute__((address_space(1))) void*)g,
                                   (__attribute__((address_space(3))) void*)l, 16, 0, 0);
}

static __device__ __forceinline__ f32x16 splat16(float x){
  f32x16 v;
#pragma unroll
  for (int i = 0; i < 16; ++i) v[i] = x;
  return v;
}

// ---------------- fp32 -> bf16 converts (one launch, 6 segments) ----------------
__global__ void __launch_bounds__(256) cvt_all(
    const float* __restrict__ x,  u16* __restrict__ xb,
    const float* __restrict__ cx, u16* __restrict__ cxb,
    const float* __restrict__ wq, u16* __restrict__ wqb,
    const float* __restrict__ wk, u16* __restrict__ wkb,
    const float* __restrict__ wv, u16* __restrict__ wvb,
    const float* __restrict__ wo, u16* __restrict__ wob)
{
  const float* in; u16* out; int n4;
  switch (blockIdx.y){
    case 0: in=x;  out=xb;  n4=(4*2048*512)/4; break;
    case 1: in=cx; out=cxb; n4=(4*1024*768)/4; break;
    case 2: in=wq; out=wqb; n4=(512*512)/4;    break;
    case 3: in=wk; out=wkb; n4=(512*768)/4;    break;
    case 4: in=wv; out=wvb; n4=(512*768)/4;    break;
    default:in=wo; out=wob; n4=(512*512)/4;    break;
  }
  int i = blockIdx.x*256 + threadIdx.x;
  const int stride = gridDim.x*256;
  for (; i < n4; i += stride){
    float4 f = ((const float4*)in)[i];
    ushort4 u;
    u.x = (u16)f2bf_u(f.x); u.y = (u16)f2bf_u(f.y);
    u.z = (u16)f2bf_u(f.z); u.w = (u16)f2bf_u(f.w);
    ((ushort4*)out)[i] = u;
  }
}

// ---------------- NT GEMM tile: C[128 x 64] = A[M,K] * B[N,K]^T ----------------
// BK=64, 4 waves (2x2), 64x32 per wave (4x2 frags of 16x16x32, 2 k-substeps).
template<int LDA, int LDB, int KK, int OM>
static __device__ __forceinline__ void gemm_tile64(
    const u16* __restrict__ Ap, const u16* __restrict__ Bp,
    void* __restrict__ Cv, int ldc, int bx, int by,
    const float* __restrict__ bias, float scale,
    u16* __restrict__ sAp, u16* __restrict__ sBp)  // sAp: 2*128*64, sBp: 2*64*64
{
  const int tid = threadIdx.x;
  const int w = tid >> 6, lane = tid & 63;
  const int wr = w >> 1, wc = w & 1;
  const long tm = (long)bx * 128;
  const long tn = (long)by * 64;

  f32x4 acc[4][2] = {};

  const int srl = lane >> 3, scc = lane & 7;  // 8 rows x 8 chunks(16B) per issue

  auto stage = [&](int kt, int bb){
#pragma unroll
    for (int i = 0; i < 4; ++i){
      const int row = w*32 + i*8 + srl;
      const int sw = scc ^ (row & 7);
      gll16(Ap + (tm + row)*LDA + kt*64 + sw*8, sAp + bb*(128*64) + (w*32 + i*8)*64);
    }
#pragma unroll
    for (int i = 0; i < 2; ++i){
      const int row = w*16 + i*8 + srl;
      const int sw = scc ^ (row & 7);
      gll16(Bp + (tn + row)*LDB + kt*64 + sw*8, sBp + bb*(64*64) + (w*16 + i*8)*64);
    }
  };

  const int fr = lane & 15, fg = lane >> 4;
  constexpr int NK = KK / 64;

  stage(0, 0);
  __syncthreads();
  for (int kt = 0; kt < NK; ++kt){
    if (kt + 1 < NK) stage(kt + 1, (kt + 1) & 1);
    const int bb = kt & 1;
    bf16x8 af[4][2], bfr[2][2];
#pragma unroll
    for (int fm = 0; fm < 4; ++fm){
      const int row = wr*64 + fm*16 + fr;
      const int swz = row & 7;
#pragma unroll
      for (int s = 0; s < 2; ++s)
        af[fm][s] = *(const bf16x8*)&sAp[bb*(128*64) + row*64 + ((s*4 + fg) ^ swz)*8];
    }
#pragma unroll
    for (int fn = 0; fn < 2; ++fn){
      const int row = wc*32 + fn*16 + fr;
      const int swz = row & 7;
#pragma unroll
      for (int s = 0; s < 2; ++s)
        bfr[fn][s] = *(const bf16x8*)&sBp[bb*(64*64) + row*64 + ((s*4 + fg) ^ swz)*8];
    }
#pragma unroll
    for (int s = 0; s < 2; ++s)
#pragma unroll
      for (int fm = 0; fm < 4; ++fm)
#pragma unroll
        for (int fn = 0; fn < 2; ++fn)
          acc[fm][fn] = MFMA16x16x32(af[fm][s], bfr[fn][s], acc[fm][fn], 0, 0, 0);
    __syncthreads();
  }

  // C fragment: col = lane&15, row = (lane>>4)*4 + reg
#pragma unroll
  for (int fm = 0; fm < 4; ++fm){
#pragma unroll
    for (int fn = 0; fn < 2; ++fn){
      const long row0 = tm + wr*64 + fm*16 + fg*4;
      const long col  = tn + wc*32 + fn*16 + fr;
      if (OM == 0){
        u16* C = (u16*)Cv;
#pragma unroll
        for (int rr = 0; rr < 4; ++rr)
          C[(row0 + rr)*ldc + col] = (u16)f2bf_u(acc[fm][fn][rr] * scale);
      } else {
        float* C = (float*)Cv;
        const float bv = bias[col];
#pragma unroll
        for (int rr = 0; rr < 4; ++rr)
          C[(row0 + rr)*ldc + col] = acc[fm][fn][rr] + bv;
      }
    }
  }
}

// ---------------- NT GEMM tile: C[128 x 128] = A[M,K] * B[N,K]^T ----------------
// BK=64, 4 waves (2x2), 64x64 per wave (4x4 frags, 2 k-substeps). 64 KB LDS.
template<int LDA, int LDB, int KK, int OM>
static __device__ __forceinline__ void gemm_tile128(
    const u16* __restrict__ Ap, const u16* __restrict__ Bp,
    void* __restrict__ Cv, int ldc, int bx, int by,
    const float* __restrict__ bias, float scale,
    u16* __restrict__ sAp, u16* __restrict__ sBp)  // each 2*128*64 u16
{
  const int tid = threadIdx.x;
  const int w = tid >> 6, lane = tid & 63;
  const int wr = w >> 1, wc = w & 1;
  const long tm = (long)bx * 128;
  const long tn = (long)by * 128;

  f32x4 acc[4][4] = {};

  const int srl = lane >> 3, scc = lane & 7;  // 8 rows x 8 chunks(16B) per issue

  auto stage = [&](int kt, int bb){
#pragma unroll
    for (int i = 0; i < 4; ++i){
      const int row = w*32 + i*8 + srl;
      const int sw = scc ^ (row & 7);
      gll16(Ap + (tm + row)*LDA + kt*64 + sw*8, sAp + bb*(128*64) + (w*32 + i*8)*64);
      gll16(Bp + (tn + row)*LDB + kt*64 + sw*8, sBp + bb*(128*64) + (w*32 + i*8)*64);
    }
  };

  const int fr = lane & 15, fg = lane >> 4;
  constexpr int NK = KK / 64;

  stage(0, 0);
  __syncthreads();
  for (int kt = 0; kt < NK; ++kt){
    if (kt + 1 < NK) stage(kt + 1, (kt + 1) & 1);
    const int bb = kt & 1;
    bf16x8 af[4][2], bfr[4][2];
#pragma unroll
    for (int fm = 0; fm < 4; ++fm){
      const int row = wr*64 + fm*16 + fr;
      const int swz = row & 7;
#pragma unroll
      for (int s = 0; s < 2; ++s)
        af[fm][s] = *(const bf16x8*)&sAp[bb*(128*64) + row*64 + ((s*4 + fg) ^ swz)*8];
    }
#pragma unroll
    for (int fn = 0; fn < 4; ++fn){
      const int row = wc*64 + fn*16 + fr;
      const int swz = row & 7;
#pragma unroll
      for (int s = 0; s < 2; ++s)
        bfr[fn][s] = *(const bf16x8*)&sBp[bb*(128*64) + row*64 + ((s*4 + fg) ^ swz)*8];
    }
#pragma unroll
    for (int s = 0; s < 2; ++s)
#pragma unroll
      for (int fm = 0; fm < 4; ++fm)
#pragma unroll
        for (int fn = 0; fn < 4; ++fn)
          acc[fm][fn] = MFMA16x16x32(af[fm][s], bfr[fn][s], acc[fm][fn], 0, 0, 0);
    __syncthreads();
  }

#pragma unroll
  for (int fm = 0; fm < 4; ++fm){
#pragma unroll
    for (int fn = 0; fn < 4; ++fn){
      const long row0 = tm + wr*64 + fm*16 + fg*4;
      const long col  = tn + wc*64 + fn*16 + fr;
      if (OM == 0){
        u16* C = (u16*)Cv;
#pragma unroll
        for (int rr = 0; rr < 4; ++rr)
          C[(row0 + rr)*ldc + col] = (u16)f2bf_u(acc[fm][fn][rr] * scale);
      } else {
        float* C = (float*)Cv;
        const float bv = bias[col];
#pragma unroll
        for (int rr = 0; rr < 4; ++rr)
          C[(row0 + rr)*ldc + col] = acc[fm][fn][rr] + bv;
      }
    }
  }
}

// ---------------- fused q/k/v projections: 512 blocks (one resident round) ----------
// q: 256 tiles (64x4), k: 128 tiles (32x4), v: 128 tiles (4 x (4x8) per batch)
__global__ __launch_bounds__(256, 2) void proj_fused(
    const u16* __restrict__ xb,  const u16* __restrict__ cxb,
    const u16* __restrict__ wqb, const u16* __restrict__ wkb,
    const u16* __restrict__ wvb,
    u16* __restrict__ qb, u16* __restrict__ kb, u16* __restrict__ vtb,
    float qscale)
{
  __shared__ u16 sA[2*128*64];
  __shared__ u16 sB[2*128*64];
  const int bid = blockIdx.x;
  const int lid = (bid & 7)*64 + (bid >> 3);   // bijective XCD swizzle (512%8==0)
  if (lid < 256){
    gemm_tile128<512,512,512,0>(xb, wqb, (void*)qb, 512, lid >> 2, lid & 3,
                                nullptr, qscale, sA, sB);
  } else if (lid < 384){
    const int t = lid - 256;
    gemm_tile128<768,768,768,0>(cxb, wkb, (void*)kb, 512, t >> 2, t & 3,
                                nullptr, 1.0f, sA, sB);
  } else {
    const int t = lid - 384, z = t >> 5, r = t & 31;
    gemm_tile128<768,768,768,0>(wvb, cxb + (long)z*1024*768,
                                (void*)(vtb + (long)z*512*1024), 1024,
                                r >> 3, r & 7, nullptr, 1.0f, sA, sB);
  }
}

// ---------------- final projection: y = aout @ Wo^T + bo (fp32) ----------------
__global__ __launch_bounds__(256, 3) void gemm_out(
    const u16* __restrict__ ab, const u16* __restrict__ wob,
    float* __restrict__ out, const float* __restrict__ bias)
{
  __shared__ u16 sA[2*128*64];
  __shared__ u16 sB[2*64*64];
  const int bid = blockIdx.x;
  const int lid = (bid & 7)*64 + (bid >> 3);    // 512 blocks
  gemm_tile64<512,512,512,1>(ab, wob, (void*)out, 512, lid >> 3, lid & 7,
                             bias, 1.0f, sA, sB);
}

// ---------------- flash attention, 32x32 MFMA, fixed-shift softmax ----------------
// v2: each wave owns 64 q-rows (2 x 32-row fragments) so every K/V fragment read
// from LDS feeds TWO MFMAs (was 1:1 read:MFMA -> LDS-read-bound at ~1536 cyc/iter/CU).
// Block = 4 waves = 256 q rows; grid = 256 blocks (1/CU, 4 waves/CU).
// 4-deep LDS ring, counted vmcnt (never 0 in steady state), raw s_barrier.
// Per iter: stage(kb+2) -> vmcnt(8) [own stage(kb) landed] -> s_barrier -> compute(kb).
// Ring safety: a wave ahead by one barrier interval writes buf (kb+3)&3, never
// the buf (kb&3) a slower wave still reads. Schedule identical to verified round 4.
__global__ __launch_bounds__(256, 1) void attn_fwd(
    const u16* __restrict__ Q,   // [B*2048, 512], pre-scaled by 0.125*log2(e)
    const u16* __restrict__ Kb,  // [B*1024, 512]
    const u16* __restrict__ Vt,  // [B, 512, 1024]  (V^T per batch)
    u16* __restrict__ O)         // [B*2048, 512]
{
  const int bid = blockIdx.x;
  const int lid = (bid & 7)*32 + (bid >> 3);   // XCD-contiguous chunks (256%8==0)
  const int qx = lid & 7, hh = (lid >> 3) & 7, b = lid >> 6;
  const int w = threadIdx.x >> 6, lane = threadIdx.x & 63;
  const int q31 = lane & 31, hi = lane >> 5;
  const int q0 = qx*256 + w*64;                // wave's 64 q-rows

  __shared__ u16 sK[4][64*64];   // [m][d], chunk-swizzled by row&7
  __shared__ u16 sV[4][64*64];   // [d][m]
  __shared__ float sLs[8*32];    // 4 waves x 2 j-frags x 32 q

  bf16x8 qf[2][4];
#pragma unroll
  for (int j = 0; j < 2; ++j){
    const u16* qrow = Q + (long)(b*2048 + q0 + j*32 + q31)*512 + hh*64;
#pragma unroll
    for (int ks = 0; ks < 4; ++ks)
      qf[j][ks] = *(const bf16x8*)(qrow + ks*16 + hi*8);
  }

  f32x16 o[2][2] = {{splat16(0.f), splat16(0.f)}, {splat16(0.f), splat16(0.f)}};
  float lsum0 = 0.f, lsum1 = 0.f;

  const int srl = lane >> 3, scc = lane & 7;

  auto stage = [&](int kbv, int bb){
#pragma unroll
    for (int i = 0; i < 2; ++i){
      const int row = w*16 + i*8 + srl;          // 0..63
      const int sw = scc ^ (row & 7);
      gll16(Kb + (long)(b*1024 + kbv*64 + row)*512 + hh*64 + sw*8,
            &sK[bb][(w*16 + i*8)*64]);
      gll16(Vt + (long)(b*512 + hh*64 + row)*1024 + kbv*64 + sw*8,
            &sV[bb][(w*16 + i*8)*64]);
    }
  };

  stage(0, 0);
  stage(1, 1);

  for (int kb = 0; kb < 16; ++kb){
    if (kb + 2 < 16) stage(kb + 2, (kb + 2) & 3);
    // wait until this wave's stage(kb) has landed (4 loads per stage):
    if (kb <= 13)      asm volatile("s_waitcnt vmcnt(8)" ::: "memory");
    else if (kb == 14) asm volatile("s_waitcnt vmcnt(4)" ::: "memory");
    else               asm volatile("s_waitcnt vmcnt(0)" ::: "memory");
    __builtin_amdgcn_s_barrier();
    asm volatile("" ::: "memory");
    const u16* sKp = sK[kb & 3];
    const u16* sVp = sV[kb & 3];

#pragma unroll
    for (int mt = 0; mt < 2; ++mt){
      // ---- S^T = K * Q^T for both q-frags; each kf read feeds 2 MFMAs ----
      f32x16 s0 = splat16(-16.f), s1 = splat16(-16.f);
      const int row = mt*32 + q31;
      const int swz = row & 7;
      __builtin_amdgcn_s_setprio(1);
#pragma unroll
      for (int ks = 0; ks < 4; ++ks){
        bf16x8 kf = *(const bf16x8*)&sKp[row*64 + ((ks*2 + hi) ^ swz)*8];
        s0 = MFMA32x32x16(kf, qf[0][ks], s0, 0, 0, 0);
        s1 = MFMA32x32x16(kf, qf[1][ks], s1, 0, 0, 0);
      }
      __builtin_amdgcn_s_setprio(0);

      // ---- p = exp2(s), lsum accumulate, pack pairs to bf16 ----
      unsigned pk0[8], pk1[8];
#pragma unroll
      for (int r = 0; r < 16; ++r){ s0[r] = EXP2(s0[r]); lsum0 += s0[r]; }
#pragma unroll
      for (int r = 0; r < 16; ++r){ s1[r] = EXP2(s1[r]); lsum1 += s1[r]; }
#pragma unroll
      for (int p2 = 0; p2 < 8; ++p2){
        union { bf16x2 h; unsigned u; } t0, t1;
        t0.h[0] = (__bf16)s0[2*p2]; t0.h[1] = (__bf16)s0[2*p2 + 1]; pk0[p2] = t0.u;
        t1.h[0] = (__bf16)s1[2*p2]; t1.h[1] = (__bf16)s1[2*p2 + 1]; pk1[p2] = t1.u;
      }

      // ---- PV: each bv read feeds 2 MFMAs (one per q-frag) ----
#pragma unroll
      for (int sl = 0; sl < 2; ++sl){
        union { unsigned u[4]; bf16x8 v; } pa0, pa1;
        {
          const unsigned ca = pk0[sl*4 + 0], cb = pk0[sl*4 + 1];
          const unsigned cc = pk0[sl*4 + 2], cd = pk0[sl*4 + 3];
          const unsigned ya = hi ? ca : cc;
          const unsigned za = (unsigned)__shfl_xor((int)ya, 32);
          const unsigned yb = hi ? cb : cd;
          const unsigned zb = (unsigned)__shfl_xor((int)yb, 32);
          pa0.u[0] = hi ? za : ca;
          pa0.u[1] = hi ? zb : cb;
          pa0.u[2] = hi ? cc : za;
          pa0.u[3] = hi ? cd : zb;
        }
        {
          const unsigned ca = pk1[sl*4 + 0], cb = pk1[sl*4 + 1];
          const unsigned cc = pk1[sl*4 + 2], cd = pk1[sl*4 + 3];
          const unsigned ya = hi ? ca : cc;
          const unsigned za = (unsigned)__shfl_xor((int)ya, 32);
          const unsigned yb = hi ? cb : cd;
          const unsigned zb = (unsigned)__shfl_xor((int)yb, 32);
          pa1.u[0] = hi ? za : ca;
          pa1.u[1] = hi ? zb : cb;
          pa1.u[2] = hi ? cc : za;
          pa1.u[3] = hi ? cd : zb;
        }
        const int s = mt*2 + sl;
        __builtin_amdgcn_s_setprio(1);
#pragma unroll
        for (int fd = 0; fd < 2; ++fd){
          const int vrow = fd*32 + q31;
          bf16x8 bv = *(const bf16x8*)&sVp[vrow*64 + (((s*2 + hi) ^ (vrow & 7)))*8];
          o[0][fd] = MFMA32x32x16(pa0.v, bv, o[0][fd], 0, 0, 0);
          o[1][fd] = MFMA32x32x16(pa1.v, bv, o[1][fd], 0, 0, 0);
        }
        __builtin_amdgcn_s_setprio(0);
      }
    }
    asm volatile("" ::: "memory");
  }

  // ---- normalize ----
  lsum0 += __shfl_xor(lsum0, 32);
  lsum1 += __shfl_xor(lsum1, 32);
  sLs[(w*2 + 0)*32 + q31] = lsum0;
  sLs[(w*2 + 1)*32 + q31] = lsum1;
  __syncthreads();

#pragma unroll
  for (int j = 0; j < 2; ++j){
    f32x4 inv[4];
#pragma unroll
    for (int g = 0; g < 4; ++g){
      f32x4 ls = *(const f32x4*)&sLs[(w*2 + j)*32 + 8*g + 4*hi];
#pragma unroll
      for (int e = 0; e < 4; ++e) inv[g][e] = 1.0f / ls[e];
    }
    u16* orow = O + (long)(b*2048 + q0 + j*32)*512 + hh*64;
#pragma unroll
    for (int fd = 0; fd < 2; ++fd){
#pragma unroll
      for (int r = 0; r < 16; ++r){
        const int q = (r & 3) + 8*(r >> 2) + 4*hi;
        const float val = o[j][fd][r] * inv[r >> 2][r & 3];
        orow[(long)q*512 + fd*32 + q31] = (u16)f2bf_u(val);
      }
    }
  }
}

// ---------------- launch ----------------
extern "C" void kernel_launch(void* const* d_in, const int* in_sizes, int n_in,
                              void* d_out, int out_size, void* d_ws, size_t ws_size,
                              hipStream_t stream)
{
  (void)in_sizes; (void)n_in; (void)out_size; (void)ws_size;
  const float* x   = (const float*)d_in[0];
  const float* ctx = (const float*)d_in[1];
  const float* Wq  = (const float*)d_in[2];
  const float* Wk  = (const float*)d_in[3];
  const float* Wv  = (const float*)d_in[4];
  const float* Wo  = (const float*)d_in[5];
  const float* bo  = (const float*)d_in[6];
  float* out = (float*)d_out;

  char* ws = (char*)d_ws;
  u16* xb  = (u16*)(ws + 0);          // x bf16        [8192,512]   8.0 MB
  u16* cxb = (u16*)(ws + 8388608);    // ctx bf16      [4096,768]   6.0 MB
  u16* wqb = (u16*)(ws + 14680064);   // Wq bf16       [512,512]
  u16* wkb = (u16*)(ws + 15204352);   // Wk bf16       [512,768]
  u16* wvb = (u16*)(ws + 15990784);   // Wv bf16       [512,768]
  u16* wob = (u16*)(ws + 16777216);   // Wo bf16       [512,512]
  u16* qb  = (u16*)(ws + 17301504);   // q bf16 (pre-scaled) [8192,512] 8.0 MB
  u16* kb  = (u16*)(ws + 25690112);   // k bf16        [4096,512]   4.0 MB
  u16* vtb = (u16*)(ws + 29884416);   // v^T bf16      [4,512,1024] 4.0 MB
  u16* ab  = (u16*)(ws + 34078720);   // attn out bf16 [8192,512]   8.0 MB

  cvt_all<<<dim3(1024, 6, 1), 256, 0, stream>>>(x, xb, ctx, cxb, Wq, wqb,
                                                Wk, wkb, Wv, wvb, Wo, wob);

  // fused q/k/v projections (q scaled by 1/8 * log2(e) for exp2-domain softmax)
  proj_fused<<<dim3(512, 1, 1), 256, 0, stream>>>(
      xb, cxb, wqb, wkb, wvb, qb, kb, vtb, 0.18033688011112042f);

  // fused attention (256 blocks, 1/CU, 2 q-frags per wave)
  attn_fwd<<<dim3(256, 1, 1), 256, 0, stream>>>(qb, kb, vtb, ab);

  // y = aout @ Wo^T + bo   (fp32 out)
  gemm_out<<<dim3(512, 1, 1), 256, 0, stream>>>(ab, wob, out, bo);
}

// Round 2
// 67.190 us; speedup vs baseline: 1.1483x; 1.1483x over previous
//
#include <hip/hip_runtime.h>

using u16 = unsigned short;
typedef __bf16 bf16x8 __attribute__((ext_vector_type(8)));
typedef __bf16 bf16x2 __attribute__((ext_vector_type(2)));
typedef float  f32x4  __attribute__((ext_vector_type(4)));
typedef float  f32x16 __attribute__((ext_vector_type(16)));

#define MFMA16x16x32 __builtin_amdgcn_mfma_f32_16x16x32_bf16
#define MFMA32x32x16 __builtin_amdgcn_mfma_f32_32x32x16_bf16

#if __has_builtin(__builtin_amdgcn_exp2f)
#define EXP2 __builtin_amdgcn_exp2f
#else
#define EXP2 exp2f
#endif

// fp32 -> bf16 round-to-nearest-even (bit math; finite inputs only)
static __device__ __forceinline__ unsigned f2bf_u(float f){
  unsigned x = __builtin_bit_cast(unsigned, f);
  return (x + 0x7fffu + ((x >> 16) & 1u)) >> 16;
}

// async global->LDS, 16B per lane; dest is wave-uniform base + lane*16
static __device__ __forceinline__ void gll16(const void* g, void* l){
  __builtin_amdgcn_global_load_lds((const __attribute__((address_space(1))) void*)g,
                                   (__attribute__((address_space(3))) void*)l, 16, 0, 0);
}

static __device__ __forceinline__ f32x16 splat16(float x){
  f32x16 v;
#pragma unroll
  for (int i = 0; i < 16; ++i) v[i] = x;
  return v;
}

// ---------------- fp32 -> bf16 converts (one launch, 6 segments) ----------------
__global__ void __launch_bounds__(256) cvt_all(
    const float* __restrict__ x,  u16* __restrict__ xb,
    const float* __restrict__ cx, u16* __restrict__ cxb,
    const float* __restrict__ wq, u16* __restrict__ wqb,
    const float* __restrict__ wk, u16* __restrict__ wkb,
    const float* __restrict__ wv, u16* __restrict__ wvb,
    const float* __restrict__ wo, u16* __restrict__ wob)
{
  const float* in; u16* out; int n4;
  switch (blockIdx.y){
    case 0: in=x;  out=xb;  n4=(4*2048*512)/4; break;
    case 1: in=cx; out=cxb; n4=(4*1024*768)/4; break;
    case 2: in=wq; out=wqb; n4=(512*512)/4;    break;
    case 3: in=wk; out=wkb; n4=(512*768)/4;    break;
    case 4: in=wv; out=wvb; n4=(512*768)/4;    break;
    default:in=wo; out=wob; n4=(512*512)/4;    break;
  }
  int i = blockIdx.x*256 + threadIdx.x;
  const int stride = gridDim.x*256;
  for (; i < n4; i += stride){
    float4 f = ((const float4*)in)[i];
    ushort4 u;
    u.x = (u16)f2bf_u(f.x); u.y = (u16)f2bf_u(f.y);
    u.z = (u16)f2bf_u(f.z); u.w = (u16)f2bf_u(f.w);
    ((ushort4*)out)[i] = u;
  }
}

// ---------------- NT GEMM tile: C[128 x 64] = A[M,K] * B[N,K]^T ----------------
// BK=64, 4 waves (2x2), 64x32 per wave (4x2 frags of 16x16x32, 2 k-substeps).
template<int LDA, int LDB, int KK, int OM>
static __device__ __forceinline__ void gemm_tile64(
    const u16* __restrict__ Ap, const u16* __restrict__ Bp,
    void* __restrict__ Cv, int ldc, int bx, int by,
    const float* __restrict__ bias, float scale,
    u16* __restrict__ sAp, u16* __restrict__ sBp)  // sAp: 2*128*64, sBp: 2*64*64
{
  const int tid = threadIdx.x;
  const int w = tid >> 6, lane = tid & 63;
  const int wr = w >> 1, wc = w & 1;
  const long tm = (long)bx * 128;
  const long tn = (long)by * 64;

  f32x4 acc[4][2] = {};

  const int srl = lane >> 3, scc = lane & 7;  // 8 rows x 8 chunks(16B) per issue

  auto stage = [&](int kt, int bb){
#pragma unroll
    for (int i = 0; i < 4; ++i){
      const int row = w*32 + i*8 + srl;
      const int sw = scc ^ (row & 7);
      gll16(Ap + (tm + row)*LDA + kt*64 + sw*8, sAp + bb*(128*64) + (w*32 + i*8)*64);
    }
#pragma unroll
    for (int i = 0; i < 2; ++i){
      const int row = w*16 + i*8 + srl;
      const int sw = scc ^ (row & 7);
      gll16(Bp + (tn + row)*LDB + kt*64 + sw*8, sBp + bb*(64*64) + (w*16 + i*8)*64);
    }
  };

  const int fr = lane & 15, fg = lane >> 4;
  constexpr int NK = KK / 64;

  stage(0, 0);
  __syncthreads();
  for (int kt = 0; kt < NK; ++kt){
    if (kt + 1 < NK) stage(kt + 1, (kt + 1) & 1);
    const int bb = kt & 1;
    bf16x8 af[4][2], bfr[2][2];
#pragma unroll
    for (int fm = 0; fm < 4; ++fm){
      const int row = wr*64 + fm*16 + fr;
      const int swz = row & 7;
#pragma unroll
      for (int s = 0; s < 2; ++s)
        af[fm][s] = *(const bf16x8*)&sAp[bb*(128*64) + row*64 + ((s*4 + fg) ^ swz)*8];
    }
#pragma unroll
    for (int fn = 0; fn < 2; ++fn){
      const int row = wc*32 + fn*16 + fr;
      const int swz = row & 7;
#pragma unroll
      for (int s = 0; s < 2; ++s)
        bfr[fn][s] = *(const bf16x8*)&sBp[bb*(64*64) + row*64 + ((s*4 + fg) ^ swz)*8];
    }
#pragma unroll
    for (int s = 0; s < 2; ++s)
#pragma unroll
      for (int fm = 0; fm < 4; ++fm)
#pragma unroll
        for (int fn = 0; fn < 2; ++fn)
          acc[fm][fn] = MFMA16x16x32(af[fm][s], bfr[fn][s], acc[fm][fn], 0, 0, 0);
    __syncthreads();
  }

  // C fragment: col = lane&15, row = (lane>>4)*4 + reg
#pragma unroll
  for (int fm = 0; fm < 4; ++fm){
#pragma unroll
    for (int fn = 0; fn < 2; ++fn){
      const long row0 = tm + wr*64 + fm*16 + fg*4;
      const long col  = tn + wc*32 + fn*16 + fr;
      if (OM == 0){
        u16* C = (u16*)Cv;
#pragma unroll
        for (int rr = 0; rr < 4; ++rr)
          C[(row0 + rr)*ldc + col] = (u16)f2bf_u(acc[fm][fn][rr] * scale);
      } else {
        float* C = (float*)Cv;
        const float bv = bias[col];
#pragma unroll
        for (int rr = 0; rr < 4; ++rr)
          C[(row0 + rr)*ldc + col] = acc[fm][fn][rr] + bv;
      }
    }
  }
}

// ---------------- NT GEMM tile: C[128 x 128] = A[M,K] * B[N,K]^T ----------------
// BK=64, 4 waves (2x2), 64x64 per wave (4x4 frags, 2 k-substeps). 64 KB LDS.
template<int LDA, int LDB, int KK, int OM>
static __device__ __forceinline__ void gemm_tile128(
    const u16* __restrict__ Ap, const u16* __restrict__ Bp,
    void* __restrict__ Cv, int ldc, int bx, int by,
    const float* __restrict__ bias, float scale,
    u16* __restrict__ sAp, u16* __restrict__ sBp)  // each 2*128*64 u16
{
  const int tid = threadIdx.x;
  const int w = tid >> 6, lane = tid & 63;
  const int wr = w >> 1, wc = w & 1;
  const long tm = (long)bx * 128;
  const long tn = (long)by * 128;

  f32x4 acc[4][4] = {};

  const int srl = lane >> 3, scc = lane & 7;  // 8 rows x 8 chunks(16B) per issue

  auto stage = [&](int kt, int bb){
#pragma unroll
    for (int i = 0; i < 4; ++i){
      const int row = w*32 + i*8 + srl;
      const int sw = scc ^ (row & 7);
      gll16(Ap + (tm + row)*LDA + kt*64 + sw*8, sAp + bb*(128*64) + (w*32 + i*8)*64);
      gll16(Bp + (tn + row)*LDB + kt*64 + sw*8, sBp + bb*(128*64) + (w*32 + i*8)*64);
    }
  };

  const int fr = lane & 15, fg = lane >> 4;
  constexpr int NK = KK / 64;

  stage(0, 0);
  __syncthreads();
  for (int kt = 0; kt < NK; ++kt){
    if (kt + 1 < NK) stage(kt + 1, (kt + 1) & 1);
    const int bb = kt & 1;
    bf16x8 af[4][2], bfr[4][2];
#pragma unroll
    for (int fm = 0; fm < 4; ++fm){
      const int row = wr*64 + fm*16 + fr;
      const int swz = row & 7;
#pragma unroll
      for (int s = 0; s < 2; ++s)
        af[fm][s] = *(const bf16x8*)&sAp[bb*(128*64) + row*64 + ((s*4 + fg) ^ swz)*8];
    }
#pragma unroll
    for (int fn = 0; fn < 4; ++fn){
      const int row = wc*64 + fn*16 + fr;
      const int swz = row & 7;
#pragma unroll
      for (int s = 0; s < 2; ++s)
        bfr[fn][s] = *(const bf16x8*)&sBp[bb*(128*64) + row*64 + ((s*4 + fg) ^ swz)*8];
    }
#pragma unroll
    for (int s = 0; s < 2; ++s)
#pragma unroll
      for (int fm = 0; fm < 4; ++fm)
#pragma unroll
        for (int fn = 0; fn < 4; ++fn)
          acc[fm][fn] = MFMA16x16x32(af[fm][s], bfr[fn][s], acc[fm][fn], 0, 0, 0);
    __syncthreads();
  }

#pragma unroll
  for (int fm = 0; fm < 4; ++fm){
#pragma unroll
    for (int fn = 0; fn < 4; ++fn){
      const long row0 = tm + wr*64 + fm*16 + fg*4;
      const long col  = tn + wc*64 + fn*16 + fr;
      if (OM == 0){
        u16* C = (u16*)Cv;
#pragma unroll
        for (int rr = 0; rr < 4; ++rr)
          C[(row0 + rr)*ldc + col] = (u16)f2bf_u(acc[fm][fn][rr] * scale);
      } else {
        float* C = (float*)Cv;
        const float bv = bias[col];
#pragma unroll
        for (int rr = 0; rr < 4; ++rr)
          C[(row0 + rr)*ldc + col] = acc[fm][fn][rr] + bv;
      }
    }
  }
}

// ---------------- fused q/k/v projections: 512 blocks (one resident round) ----------
__global__ __launch_bounds__(256, 2) void proj_fused(
    const u16* __restrict__ xb,  const u16* __restrict__ cxb,
    const u16* __restrict__ wqb, const u16* __restrict__ wkb,
    const u16* __restrict__ wvb,
    u16* __restrict__ qb, u16* __restrict__ kb, u16* __restrict__ vtb,
    float qscale)
{
  __shared__ u16 sA[2*128*64];
  __shared__ u16 sB[2*128*64];
  const int bid = blockIdx.x;
  const int lid = (bid & 7)*64 + (bid >> 3);   // bijective XCD swizzle (512%8==0)
  if (lid < 256){
    gemm_tile128<512,512,512,0>(xb, wqb, (void*)qb, 512, lid >> 2, lid & 3,
                                nullptr, qscale, sA, sB);
  } else if (lid < 384){
    const int t = lid - 256;
    gemm_tile128<768,768,768,0>(cxb, wkb, (void*)kb, 512, t >> 2, t & 3,
                                nullptr, 1.0f, sA, sB);
  } else {
    const int t = lid - 384, z = t >> 5, r = t & 31;
    gemm_tile128<768,768,768,0>(wvb, cxb + (long)z*1024*768,
                                (void*)(vtb + (long)z*512*1024), 1024,
                                r >> 3, r & 7, nullptr, 1.0f, sA, sB);
  }
}

// ---------------- final projection: y = aout @ Wo^T + bo (fp32) ----------------
__global__ __launch_bounds__(256, 3) void gemm_out(
    const u16* __restrict__ ab, const u16* __restrict__ wob,
    float* __restrict__ out, const float* __restrict__ bias)
{
  __shared__ u16 sA[2*128*64];
  __shared__ u16 sB[2*64*64];
  const int bid = blockIdx.x;
  const int lid = (bid & 7)*64 + (bid >> 3);    // 512 blocks
  gemm_tile64<512,512,512,1>(ab, wob, (void*)out, 512, lid >> 3, lid & 7,
                             bias, 1.0f, sA, sB);
}

// ---------------- flash attention, 32x32 MFMA, fixed-shift softmax ----------------
// v3: 8 waves/block, 256 blocks (1 block/CU, 2 waves/SIMD — round-0 occupancy),
// KEEPING the 2x fragment reuse from v2 (each wave: 64 q-rows, every K/V LDS read
// feeds two MFMAs). KV dimension split across wave pairs: waves 0-3 (kvg=0) do
// even KV tiles, waves 4-7 (kvg=1) do odd tiles, same q-rows; partial O/lsum
// combined through LDS at the end.
// Ring: 8 tile-slots (128 KB). Pair-prefetch 2 ahead: concurrent window spans
// compute(t-1) || stage(t+2): slot distance 6 mod 8 != 0 -> safe (mod-4 collides).
// vmcnt ladder preserved: 4 loads/wave/pair-stage -> vmcnt(8)/(4)/(0).
__global__ __launch_bounds__(512, 2) void attn_fwd(
    const u16* __restrict__ Q,   // [B*2048, 512], pre-scaled by 0.125*log2(e)
    const u16* __restrict__ Kb,  // [B*1024, 512]
    const u16* __restrict__ Vt,  // [B, 512, 1024]  (V^T per batch)
    u16* __restrict__ O)         // [B*2048, 512]
{
  const int bid = blockIdx.x;
  const int lid = (bid & 7)*32 + (bid >> 3);   // XCD-contiguous chunks (256%8==0)
  const int qx = lid & 7, hh = (lid >> 3) & 7, b = lid >> 6;
  const int w = threadIdx.x >> 6, lane = threadIdx.x & 63;
  const int q31 = lane & 31, hi = lane >> 5;
  const int w4 = w & 3, kvg = w >> 2;
  const int q0 = qx*256 + w4*64;               // wave's 64 q-rows

  __shared__ u16 sK[8][64*64];   // [m][d], chunk-swizzled by row&7; 64 KB
  __shared__ u16 sV[8][64*64];   // [d][m]; 64 KB
  __shared__ float sLsP[16*32];  // per-wave partial lsums (8 waves x 2 frags x 32)
  __shared__ float sLsT[8*32];   // totals (4 waves x 2 frags x 32)

  bf16x8 qf[2][4];
#pragma unroll
  for (int j = 0; j < 2; ++j){
    const u16* qrow = Q + (long)(b*2048 + q0 + j*32 + q31)*512 + hh*64;
#pragma unroll
    for (int ks = 0; ks < 4; ++ks)
      qf[j][ks] = *(const bf16x8*)(qrow + ks*16 + hi*8);
  }

  f32x16 o[2][2] = {{splat16(0.f), splat16(0.f)}, {splat16(0.f), splat16(0.f)}};
  float lsum0 = 0.f, lsum1 = 0.f;

  const int srl = lane >> 3, scc = lane & 7;

  // stage one tile-pair (tiles 2u, 2u+1): waves 0-3 stage tile 2u, waves 4-7
  // stage tile 2u+1; 4 gll16 per wave (2 K chunks + 2 V chunks).
  auto stagePair = [&](int u){
    const int tv = 2*u + kvg;
    const int sl = tv & 7;
#pragma unroll
    for (int i = 0; i < 2; ++i){
      const int row = w4*16 + i*8 + srl;        // 0..63 across the 4 waves
      const int sw = scc ^ (row & 7);
      gll16(Kb + (long)(b*1024 + tv*64 + row)*512 + hh*64 + sw*8,
            &sK[sl][(w4*16 + i*8)*64]);
      gll16(Vt + (long)(b*512 + hh*64 + row)*1024 + tv*64 + sw*8,
            &sV[sl][(w4*16 + i*8)*64]);
    }
  };

  stagePair(0);
  stagePair(1);

  for (int t = 0; t < 8; ++t){
    if (t + 2 < 8) stagePair(t + 2);
    // wait until this wave's stagePair(t) has landed (4 loads per pair-stage):
    if (t <= 5)      asm volatile("s_waitcnt vmcnt(8)" ::: "memory");
    else if (t == 6) asm volatile("s_waitcnt vmcnt(4)" ::: "memory");
    else             asm volatile("s_waitcnt vmcnt(0)" ::: "memory");
    __builtin_amdgcn_s_barrier();
    asm volatile("" ::: "memory");
    const int tv = 2*t + kvg;                   // this wave's tile
    const int sl = tv & 7;
    const u16* sKp = sK[sl];
    const u16* sVp = sV[sl];

#pragma unroll
    for (int mt = 0; mt < 2; ++mt){
      // ---- S^T = K * Q^T for both q-frags; each kf read feeds 2 MFMAs ----
      f32x16 s0 = splat16(-16.f), s1 = splat16(-16.f);
      const int row = mt*32 + q31;
      const int swz = row & 7;
      __builtin_amdgcn_s_setprio(1);
#pragma unroll
      for (int ks = 0; ks < 4; ++ks){
        bf16x8 kf = *(const bf16x8*)&sKp[row*64 + ((ks*2 + hi) ^ swz)*8];
        s0 = MFMA32x32x16(kf, qf[0][ks], s0, 0, 0, 0);
        s1 = MFMA32x32x16(kf, qf[1][ks], s1, 0, 0, 0);
      }
      __builtin_amdgcn_s_setprio(0);

      // ---- p = exp2(s), lsum accumulate, pack pairs to bf16 ----
      unsigned pk0[8], pk1[8];
#pragma unroll
      for (int r = 0; r < 16; ++r){ s0[r] = EXP2(s0[r]); lsum0 += s0[r]; }
#pragma unroll
      for (int r = 0; r < 16; ++r){ s1[r] = EXP2(s1[r]); lsum1 += s1[r]; }
#pragma unroll
      for (int p2 = 0; p2 < 8; ++p2){
        union { bf16x2 h; unsigned u; } t0, t1;
        t0.h[0] = (__bf16)s0[2*p2]; t0.h[1] = (__bf16)s0[2*p2 + 1]; pk0[p2] = t0.u;
        t1.h[0] = (__bf16)s1[2*p2]; t1.h[1] = (__bf16)s1[2*p2 + 1]; pk1[p2] = t1.u;
      }

      // ---- PV: each bv read feeds 2 MFMAs (one per q-frag) ----
#pragma unroll
      for (int sl2 = 0; sl2 < 2; ++sl2){
        union { unsigned u[4]; bf16x8 v; } pa0, pa1;
        {
          const unsigned ca = pk0[sl2*4 + 0], cb = pk0[sl2*4 + 1];
          const unsigned cc = pk0[sl2*4 + 2], cd = pk0[sl2*4 + 3];
          const unsigned ya = hi ? ca : cc;
          const unsigned za = (unsigned)__shfl_xor((int)ya, 32);
          const unsigned yb = hi ? cb : cd;
          const unsigned zb = (unsigned)__shfl_xor((int)yb, 32);
          pa0.u[0] = hi ? za : ca;
          pa0.u[1] = hi ? zb : cb;
          pa0.u[2] = hi ? cc : za;
          pa0.u[3] = hi ? cd : zb;
        }
        {
          const unsigned ca = pk1[sl2*4 + 0], cb = pk1[sl2*4 + 1];
          const unsigned cc = pk1[sl2*4 + 2], cd = pk1[sl2*4 + 3];
          const unsigned ya = hi ? ca : cc;
          const unsigned za = (unsigned)__shfl_xor((int)ya, 32);
          const unsigned yb = hi ? cb : cd;
          const unsigned zb = (unsigned)__shfl_xor((int)yb, 32);
          pa1.u[0] = hi ? za : ca;
          pa1.u[1] = hi ? zb : cb;
          pa1.u[2] = hi ? cc : za;
          pa1.u[3] = hi ? cd : zb;
        }
        const int s = mt*2 + sl2;
        __builtin_amdgcn_s_setprio(1);
#pragma unroll
        for (int fd = 0; fd < 2; ++fd){
          const int vrow = fd*32 + q31;
          bf16x8 bv = *(const bf16x8*)&sVp[vrow*64 + (((s*2 + hi) ^ (vrow & 7)))*8];
          o[0][fd] = MFMA32x32x16(pa0.v, bv, o[0][fd], 0, 0, 0);
          o[1][fd] = MFMA32x32x16(pa1.v, bv, o[1][fd], 0, 0, 0);
        }
        __builtin_amdgcn_s_setprio(0);
      }
    }
    asm volatile("" ::: "memory");
  }

  // ---- fold hi-halves of lsum, publish partials ----
  lsum0 += __shfl_xor(lsum0, 32);
  lsum1 += __shfl_xor(lsum1, 32);
  sLsP[(w*2 + 0)*32 + q31] = lsum0;
  sLsP[(w*2 + 1)*32 + q31] = lsum1;
  __syncthreads();   // all ring reads done; partial lsums visible

  // ---- combine wave-pair partials through LDS (aliased over dead ring) ----
  // layout: frag f in [0,16): 64 lanes x 20-word stride (16 used + 4 pad; the pad
  // breaks the 16-way bank conflict of a pure 16-word stride down to 8-way).
  float* sO = (float*)&sK[0][0];   // 16 frags * 64 * 20 * 4B = 80 KB <= 128 KB
  if (w >= 4){
#pragma unroll
    for (int j = 0; j < 2; ++j){
#pragma unroll
      for (int fd = 0; fd < 2; ++fd){
        float* p = sO + ((((w - 4)*2 + j)*2 + fd)*64*20) + lane*20;
#pragma unroll
        for (int k = 0; k < 4; ++k){
          f32x4 t4;
#pragma unroll
          for (int e = 0; e < 4; ++e) t4[e] = o[j][fd][4*k + e];
          *(f32x4*)(p + 4*k) = t4;
        }
      }
    }
  }
  __syncthreads();   // sO visible to group 0

  if (w < 4){
#pragma unroll
    for (int j = 0; j < 2; ++j){
#pragma unroll
      for (int fd = 0; fd < 2; ++fd){
        const float* p = sO + (((w*2 + j)*2 + fd)*64*20) + lane*20;
#pragma unroll
        for (int k = 0; k < 4; ++k){
          f32x4 t4 = *(const f32x4*)(p + 4*k);
#pragma unroll
          for (int e = 0; e < 4; ++e) o[j][fd][4*k + e] += t4[e];
        }
      }
    }
    const float lt0 = lsum0 + sLsP[((w + 4)*2 + 0)*32 + q31];
    const float lt1 = lsum1 + sLsP[((w + 4)*2 + 1)*32 + q31];
    sLsT[(w*2 + 0)*32 + q31] = lt0;
    sLsT[(w*2 + 1)*32 + q31] = lt1;
  }
  __syncthreads();   // totals visible

  // ---- normalize + write (group 0 only) ----
  if (w < 4){
#pragma unroll
    for (int j = 0; j < 2; ++j){
      f32x4 inv[4];
#pragma unroll
      for (int g = 0; g < 4; ++g){
        f32x4 ls = *(const f32x4*)&sLsT[(w*2 + j)*32 + 8*g + 4*hi];
#pragma unroll
        for (int e = 0; e < 4; ++e) inv[g][e] = 1.0f / ls[e];
      }
      u16* orow = O + (long)(b*2048 + q0 + j*32)*512 + hh*64;
#pragma unroll
      for (int fd = 0; fd < 2; ++fd){
#pragma unroll
        for (int r = 0; r < 16; ++r){
          const int q = (r & 3) + 8*(r >> 2) + 4*hi;
          const float val = o[j][fd][r] * inv[r >> 2][r & 3];
          orow[(long)q*512 + fd*32 + q31] = (u16)f2bf_u(val);
        }
      }
    }
  }
}

// ---------------- launch ----------------
extern "C" void kernel_launch(void* const* d_in, const int* in_sizes, int n_in,
                              void* d_out, int out_size, void* d_ws, size_t ws_size,
                              hipStream_t stream)
{
  (void)in_sizes; (void)n_in; (void)out_size; (void)ws_size;
  const float* x   = (const float*)d_in[0];
  const float* ctx = (const float*)d_in[1];
  const float* Wq  = (const float*)d_in[2];
  const float* Wk  = (const float*)d_in[3];
  const float* Wv  = (const float*)d_in[4];
  const float* Wo  = (const float*)d_in[5];
  const float* bo  = (const float*)d_in[6];
  float* out = (float*)d_out;

  char* ws = (char*)d_ws;
  u16* xb  = (u16*)(ws + 0);          // x bf16        [8192,512]   8.0 MB
  u16* cxb = (u16*)(ws + 8388608);    // ctx bf16      [4096,768]   6.0 MB
  u16* wqb = (u16*)(ws + 14680064);   // Wq bf16       [512,512]
  u16* wkb = (u16*)(ws + 15204352);   // Wk bf16       [512,768]
  u16* wvb = (u16*)(ws + 15990784);   // Wv bf16       [512,768]
  u16* wob = (u16*)(ws + 16777216);   // Wo bf16       [512,512]
  u16* qb  = (u16*)(ws + 17301504);   // q bf16 (pre-scaled) [8192,512] 8.0 MB
  u16* kb  = (u16*)(ws + 25690112);   // k bf16        [4096,512]   4.0 MB
  u16* vtb = (u16*)(ws + 29884416);   // v^T bf16      [4,512,1024] 4.0 MB
  u16* ab  = (u16*)(ws + 34078720);   // attn out bf16 [8192,512]   8.0 MB

  cvt_all<<<dim3(1024, 6, 1), 256, 0, stream>>>(x, xb, ctx, cxb, Wq, wqb,
                                                Wk, wkb, Wv, wvb, Wo, wob);

  // fused q/k/v projections (q scaled by 1/8 * log2(e) for exp2-domain softmax)
  proj_fused<<<dim3(512, 1, 1), 256, 0, stream>>>(
      xb, cxb, wqb, wkb, wvb, qb, kb, vtb, 0.18033688011112042f);

  // fused attention (256 blocks x 8 waves, KV-split wave pairs)
  attn_fwd<<<dim3(256, 1, 1), 512, 0, stream>>>(qb, kb, vtb, ab);

  // y = aout @ Wo^T + bo   (fp32 out)
  gemm_out<<<dim3(512, 1, 1), 256, 0, stream>>>(ab, wob, out, bo);
}